// Round 5
// baseline (112.917 us; speedup 1.0000x reference)
//
#include <hip/hip_runtime.h>

// Problem constants (from reference)
#define BS 2
#define NF 16
#define CH 32
#define HW 16384      // 128*128
#define NM 8          // NUM_MASKS
#define NK 3          // NUM_CLASSES
#define MID 8         // NF/2

#define S 64          // spatial px per block
#define FSPLIT 4      // frame quarters across blocks (r5: was 2)
#define FPB (NF / FSPLIT)          // 4 frames per block
#define BPB (FSPLIT * (HW / S))    // partial rows per batch = 1024
#define NBLK (BS * BPB)            // 2048 blocks

// ---------------------------------------------------------------------------
// Fused kernel, round-5: FSPLIT=4 -> per-thread upfront state is 4 float4
// (16 VGPR) + acc[8] + addressing, comfortably under the 64-VGPR cap that
// __launch_bounds__(512,8) imposes (round-4's 8 float4 risked spill/cap
// pressure). 2048 blocks = 8 queued blocks/CU hides the tail.
// Extra cost: mid-frame chunk staged by 4 blocks instead of 2 (+4 MB,
// L2/L3-hit) and 2 MB partials instead of 1 MB.
// ---------------------------------------------------------------------------
__global__ __launch_bounds__(512, 8) void fused_kernel(
    const float* __restrict__ dec, const float* __restrict__ seg_w,
    const float* __restrict__ seg_b, float* __restrict__ masks_out,
    float* __restrict__ part) {
  __shared__ float mid[CH][S];    // 8 KB
  __shared__ float msk[NM][S];    // 2 KB
  __shared__ float pbuf[NM * CH]; // 1 KB

  int t = threadIdx.x;
  int bid = blockIdx.x;           // 0..2047
  int b = bid >> 10;
  int fq = (bid >> 8) & 3;        // frame quarter 0..3
  int chunk = bid & 255;
  int cs = chunk * S;

  int s = t & 15;                 // spatial lane (16 x float4 = 64 px)
  int c = t >> 4;                 // channel 0..31

  // --- 0. issue the 4 pool loads up front (hidden behind mask phase) ---
  const float* base =
      dec + (size_t)(b * NF + fq * FPB) * CH * HW + (size_t)c * HW + cs + s * 4;
  float4 x[FPB];
#pragma unroll
  for (int f = 0; f < FPB; ++f)
    x[f] = *(const float4*)(base + (size_t)f * CH * HW);

  // --- 1. stage mid-frame chunk: 1 float4/thread = 32 rows x 64 px ---
  {
    const float* midg = dec + (size_t)(b * NF + MID) * CH * HW + cs;
    *(float4*)&mid[c][s * 4] = *(const float4*)(midg + (size_t)c * HW + s * 4);
  }
  __syncthreads();

  // --- 2. masks: 512 values, 1/thread; m wave-uniform, px stride-1 ---
  {
    int m = t >> 6, px = t & 63;
    float v = seg_b[m];
#pragma unroll
    for (int cc = 0; cc < CH; ++cc) v += mid[cc][px] * seg_w[m * CH + cc];
    msk[m][px] = v;
    if (fq == 0)
      masks_out[(size_t)b * NM * HW + (size_t)m * HW + cs + px] = v;
  }
  __syncthreads();

  // --- 3. pool FMAs: m-outer keeps live mask fragment to one float4 ---
  float acc[NM];
#pragma unroll
  for (int m = 0; m < NM; ++m) {
    float4 w = *(const float4*)&msk[m][s * 4];
    float a = 0.f;
#pragma unroll
    for (int f = 0; f < FPB; ++f)
      a += x[f].x * w.x + x[f].y * w.y + x[f].z * w.z + x[f].w * w.w;
    acc[m] = a;
  }

  // --- 4. reduce across 16 spatial lanes -> LDS -> coalesced 1KB write ---
#pragma unroll
  for (int off = 8; off >= 1; off >>= 1)
#pragma unroll
    for (int m = 0; m < NM; ++m) acc[m] += __shfl_down(acc[m], off, 16);

  if (s == 0)
#pragma unroll
    for (int m = 0; m < NM; ++m) pbuf[m * CH + c] = acc[m];
  __syncthreads();
  if (t < NM * CH) part[(size_t)bid * (NM * CH) + t] = pbuf[t];
}

// ---------------------------------------------------------------------------
// Reduce + head: one block per (b,m), 1024 threads (32-way split over the
// 1024 partial rows -> 32 strided loads/thread), then the NK-logit head.
// ---------------------------------------------------------------------------
__global__ __launch_bounds__(1024) void reduce_head_kernel(
    const float* __restrict__ part, const float* __restrict__ lw,
    const float* __restrict__ lb, float* __restrict__ out) {
  __shared__ float red[32][CH];   // 4 KB
  __shared__ float pooled[CH];

  int t = threadIdx.x;
  int b = blockIdx.x >> 3;        // 0..1
  int m = blockIdx.x & 7;         // 0..7

  int c = t & 31, j = t >> 5;     // j: 32-way split over 1024 partials
  float sum = 0.f;
  const float* p = part + (size_t)b * BPB * (NM * CH) + m * CH + c;
  for (int i = j; i < BPB; i += 32)   // 32 iterations, coalesced in c
    sum += p[(size_t)i * (NM * CH)];
  red[j][c] = sum;
  __syncthreads();

  if (t < CH) {
    float v = 0.f;
#pragma unroll
    for (int jj = 0; jj < 32; ++jj) v += red[jj][t];
    pooled[t] = v * (1.0f / NF);
  }
  __syncthreads();

  if (t < NK) {
    float dot = 0.f;
#pragma unroll
    for (int cc = 0; cc < CH; ++cc) dot += pooled[cc] * lw[t * CH + cc];
    out[b * (NM * NK) + m * NK + t] = dot + lb[t];
  }
}

extern "C" void kernel_launch(void* const* d_in, const int* in_sizes, int n_in,
                              void* d_out, int out_size, void* d_ws,
                              size_t ws_size, hipStream_t stream) {
  const float* dec = (const float*)d_in[0];    // (2,16,32,128,128)
  const float* seg_w = (const float*)d_in[1];  // (8,32)
  const float* seg_b = (const float*)d_in[2];  // (8,)
  const float* lw = (const float*)d_in[3];     // (3,32)
  const float* lb = (const float*)d_in[4];     // (3,)

  float* out = (float*)d_out;
  float* logits_out = out;                // 48 floats
  float* masks_out = out + BS * NM * NK;  // 262144 floats, 192 B offset
  float* part = (float*)d_ws;             // 2048 x 256 floats = 2 MB

  fused_kernel<<<NBLK, 512, 0, stream>>>(dec, seg_w, seg_b, masks_out, part);
  reduce_head_kernel<<<BS * NM, 1024, 0, stream>>>(part, lw, lb, logits_out);
}

// Round 6
// 106.377 us; speedup vs baseline: 1.0615x; 1.0615x over previous
//
#include <hip/hip_runtime.h>

// Problem constants (from reference)
#define BS 2
#define NF 16
#define CH 32
#define HW 16384      // 128*128
#define NM 8          // NUM_MASKS
#define NK 3          // NUM_CLASSES
#define MID 8         // NF/2

#define S 64          // spatial px per block
#define FSPLIT 2      // frame halves across blocks (r6: revert to r4 value)
#define FPB (NF / FSPLIT)          // 8 frames per block
#define BPB (FSPLIT * (HW / S))    // partial rows per batch = 512
#define NBLK (BS * BPB)            // 1024 blocks

// ---------------------------------------------------------------------------
// Fused kernel, round-6: round-4 structure + LOAD-ORDER FIX.
//   vmcnt is FIFO: loads retire in issue order. Round 4 issued 8 pool loads
//   then the mid load, so the ds_write of mid (before the first barrier)
//   required vmcnt(0) == waiting for ALL 9 loads -> the mask phase was
//   serialized behind the pool prefetch. Issuing mid FIRST means the mid
//   ds_write only needs vmcnt(8): the 8 pool loads stay in flight across
//   the entire mask-compute phase (the "never wait to 0" pattern).
// ---------------------------------------------------------------------------
__global__ __launch_bounds__(512, 8) void fused_kernel(
    const float* __restrict__ dec, const float* __restrict__ seg_w,
    const float* __restrict__ seg_b, float* __restrict__ masks_out,
    float* __restrict__ part) {
  __shared__ float mid[CH][S];    // 8 KB
  __shared__ float msk[NM][S];    // 2 KB
  __shared__ float pbuf[NM * CH]; // 1 KB

  int t = threadIdx.x;
  int bid = blockIdx.x;           // 0..1023
  int b = bid >> 9;
  int fh = (bid >> 8) & 1;
  int chunk = bid & 255;
  int cs = chunk * S;

  int s = t & 15;                 // spatial lane (16 x float4 = 64 px)
  int c = t >> 4;                 // channel 0..31

  // --- 0a. mid-frame load ISSUED FIRST (oldest in the vmcnt FIFO) ---
  const float* midg = dec + (size_t)(b * NF + MID) * CH * HW + cs;
  float4 midv = *(const float4*)(midg + (size_t)c * HW + s * 4);

  // --- 0b. the 8 pool loads, issued behind mid; consumed only after the
  //         mask phase, so they hide their latency under it ---
  const float* base =
      dec + (size_t)(b * NF + fh * FPB) * CH * HW + (size_t)c * HW + cs + s * 4;
  float4 x[FPB];
#pragma unroll
  for (int f = 0; f < FPB; ++f)
    x[f] = *(const float4*)(base + (size_t)f * CH * HW);

  // --- 1. stage mid chunk to LDS (waits vmcnt for mid only) ---
  *(float4*)&mid[c][s * 4] = midv;
  __syncthreads();

  // --- 2. masks: 512 values, 1/thread; m wave-uniform, px stride-1 ---
  {
    int m = t >> 6, px = t & 63;
    float v = seg_b[m];
#pragma unroll
    for (int cc = 0; cc < CH; ++cc) v += mid[cc][px] * seg_w[m * CH + cc];
    msk[m][px] = v;
    if (fh == 0)
      masks_out[(size_t)b * NM * HW + (size_t)m * HW + cs + px] = v;
  }
  __syncthreads();

  // --- 3. pool FMAs: m-outer keeps live mask fragment to one float4 ---
  float acc[NM];
#pragma unroll
  for (int m = 0; m < NM; ++m) {
    float4 w = *(const float4*)&msk[m][s * 4];
    float a = 0.f;
#pragma unroll
    for (int f = 0; f < FPB; ++f)
      a += x[f].x * w.x + x[f].y * w.y + x[f].z * w.z + x[f].w * w.w;
    acc[m] = a;
  }

  // --- 4. reduce across 16 spatial lanes -> LDS -> coalesced 1KB write ---
#pragma unroll
  for (int off = 8; off >= 1; off >>= 1)
#pragma unroll
    for (int m = 0; m < NM; ++m) acc[m] += __shfl_down(acc[m], off, 16);

  if (s == 0)
#pragma unroll
    for (int m = 0; m < NM; ++m) pbuf[m * CH + c] = acc[m];
  __syncthreads();
  if (t < NM * CH) part[(size_t)bid * (NM * CH) + t] = pbuf[t];
}

// ---------------------------------------------------------------------------
// Reduce + head: one block per (b,m), 1024 threads (32-way split over the
// 512 partial rows -> 16 strided loads/thread), then the NK-logit head.
// ---------------------------------------------------------------------------
__global__ __launch_bounds__(1024) void reduce_head_kernel(
    const float* __restrict__ part, const float* __restrict__ lw,
    const float* __restrict__ lb, float* __restrict__ out) {
  __shared__ float red[32][CH];   // 4 KB
  __shared__ float pooled[CH];

  int t = threadIdx.x;
  int b = blockIdx.x >> 3;        // 0..1
  int m = blockIdx.x & 7;         // 0..7

  int c = t & 31, j = t >> 5;     // j: 32-way split over 512 partials
  float sum = 0.f;
  const float* p = part + (size_t)b * BPB * (NM * CH) + m * CH + c;
  for (int i = j; i < BPB; i += 32)   // 16 iterations, coalesced in c
    sum += p[(size_t)i * (NM * CH)];
  red[j][c] = sum;
  __syncthreads();

  if (t < CH) {
    float v = 0.f;
#pragma unroll
    for (int jj = 0; jj < 32; ++jj) v += red[jj][t];
    pooled[t] = v * (1.0f / NF);
  }
  __syncthreads();

  if (t < NK) {
    float dot = 0.f;
#pragma unroll
    for (int cc = 0; cc < CH; ++cc) dot += pooled[cc] * lw[t * CH + cc];
    out[b * (NM * NK) + m * NK + t] = dot + lb[t];
  }
}

extern "C" void kernel_launch(void* const* d_in, const int* in_sizes, int n_in,
                              void* d_out, int out_size, void* d_ws,
                              size_t ws_size, hipStream_t stream) {
  const float* dec = (const float*)d_in[0];    // (2,16,32,128,128)
  const float* seg_w = (const float*)d_in[1];  // (8,32)
  const float* seg_b = (const float*)d_in[2];  // (8,)
  const float* lw = (const float*)d_in[3];     // (3,32)
  const float* lb = (const float*)d_in[4];     // (3,)

  float* out = (float*)d_out;
  float* logits_out = out;                // 48 floats
  float* masks_out = out + BS * NM * NK;  // 262144 floats, 192 B offset
  float* part = (float*)d_ws;             // 1024 x 256 floats = 1 MB

  fused_kernel<<<NBLK, 512, 0, stream>>>(dec, seg_w, seg_b, masks_out, part);
  reduce_head_kernel<<<BS * NM, 1024, 0, stream>>>(part, lw, lb, logits_out);
}

// Round 7
// 103.862 us; speedup vs baseline: 1.0872x; 1.0242x over previous
//
#include <hip/hip_runtime.h>

// Problem constants (from reference)
#define BS 2
#define NF 16
#define CH 32
#define HW 16384      // 128*128
#define NM 8          // NUM_MASKS
#define NK 3          // NUM_CLASSES
#define MID 8         // NF/2

#define S 64          // spatial px per block
#define BPB (HW / S)  // partial rows per batch = 256
#define NBLK (BS * BPB)  // 512 blocks

// ---------------------------------------------------------------------------
// Fused kernel, round-7: ONE block per (b, 64-px chunk), ALL 16 frames.
//   R6 processed each tile with 2 blocks (8 frames each) -> mid staged 2x,
//   mask tile computed 2x. Here: mask computed once, dec read EXACTLY once
//   (frame 8 doubles as the mid-frame staging load), part halves to 0.5 MB.
//   Cost: 16 float4 in flight -> ~96 VGPR -> __launch_bounds__(512,4),
//   2 blocks/CU (16 waves/CU, 50%) vs R6's 100%; compensated by 2x deeper
//   per-wave memory-level parallelism (16 loads hidden under mask phase).
// ---------------------------------------------------------------------------
__global__ __launch_bounds__(512, 4) void fused_kernel(
    const float* __restrict__ dec, const float* __restrict__ seg_w,
    const float* __restrict__ seg_b, float* __restrict__ masks_out,
    float* __restrict__ part) {
  __shared__ float mid[CH][S];    // 8 KB
  __shared__ float msk[NM][S];    // 2 KB
  __shared__ float pbuf[NM * CH]; // 1 KB

  int t = threadIdx.x;
  int bid = blockIdx.x;           // 0..511
  int b = bid >> 8;
  int chunk = bid & 255;
  int cs = chunk * S;

  int s = t & 15;                 // spatial lane (16 x float4 = 64 px)
  int c = t >> 4;                 // channel 0..31

  // --- 0. issue all 16 frame loads; frame MID first (oldest in FIFO),
  //        it doubles as the mask-phase staging value ---
  const float* base = dec + ((size_t)(b * NF) * CH + c) * HW + cs + s * 4;
  float4 x[NF];
  x[MID] = *(const float4*)(base + (size_t)MID * CH * HW);
#pragma unroll
  for (int f = 0; f < NF; ++f)
    if (f != MID) x[f] = *(const float4*)(base + (size_t)f * CH * HW);

  // --- 1. stage mid chunk to LDS (reuses x[MID], no extra global load) ---
  *(float4*)&mid[c][s * 4] = x[MID];
  __syncthreads();

  // --- 2. masks: 512 values, 1/thread; computed ONCE per pixel now ---
  {
    int m = t >> 6, px = t & 63;
    float v = seg_b[m];
#pragma unroll
    for (int cc = 0; cc < CH; ++cc) v += mid[cc][px] * seg_w[m * CH + cc];
    msk[m][px] = v;
    masks_out[(size_t)b * NM * HW + (size_t)m * HW + cs + px] = v;
  }
  __syncthreads();

  // --- 3. pool FMAs over all 16 frames; m-outer, 8 independent chains ---
  float acc[NM];
#pragma unroll
  for (int m = 0; m < NM; ++m) {
    float4 w = *(const float4*)&msk[m][s * 4];
    float a = 0.f;
#pragma unroll
    for (int f = 0; f < NF; ++f)
      a += x[f].x * w.x + x[f].y * w.y + x[f].z * w.z + x[f].w * w.w;
    acc[m] = a;
  }

  // --- 4. reduce across 16 spatial lanes -> LDS -> coalesced 1KB write ---
#pragma unroll
  for (int off = 8; off >= 1; off >>= 1)
#pragma unroll
    for (int m = 0; m < NM; ++m) acc[m] += __shfl_down(acc[m], off, 16);

  if (s == 0)
#pragma unroll
    for (int m = 0; m < NM; ++m) pbuf[m * CH + c] = acc[m];
  __syncthreads();
  if (t < NM * CH) part[(size_t)bid * (NM * CH) + t] = pbuf[t];
}

// ---------------------------------------------------------------------------
// Reduce + head: one block per (b,m), 1024 threads (32-way split over the
// 256 partial rows -> 8 strided loads/thread), then the NK-logit head.
// ---------------------------------------------------------------------------
__global__ __launch_bounds__(1024) void reduce_head_kernel(
    const float* __restrict__ part, const float* __restrict__ lw,
    const float* __restrict__ lb, float* __restrict__ out) {
  __shared__ float red[32][CH];   // 4 KB
  __shared__ float pooled[CH];

  int t = threadIdx.x;
  int b = blockIdx.x >> 3;        // 0..1
  int m = blockIdx.x & 7;         // 0..7

  int c = t & 31, j = t >> 5;     // j: 32-way split over 256 partials
  float sum = 0.f;
  const float* p = part + (size_t)b * BPB * (NM * CH) + m * CH + c;
  for (int i = j; i < BPB; i += 32)   // 8 iterations, coalesced in c
    sum += p[(size_t)i * (NM * CH)];
  red[j][c] = sum;
  __syncthreads();

  if (t < CH) {
    float v = 0.f;
#pragma unroll
    for (int jj = 0; jj < 32; ++jj) v += red[jj][t];
    pooled[t] = v * (1.0f / NF);
  }
  __syncthreads();

  if (t < NK) {
    float dot = 0.f;
#pragma unroll
    for (int cc = 0; cc < CH; ++cc) dot += pooled[cc] * lw[t * CH + cc];
    out[b * (NM * NK) + m * NK + t] = dot + lb[t];
  }
}

extern "C" void kernel_launch(void* const* d_in, const int* in_sizes, int n_in,
                              void* d_out, int out_size, void* d_ws,
                              size_t ws_size, hipStream_t stream) {
  const float* dec = (const float*)d_in[0];    // (2,16,32,128,128)
  const float* seg_w = (const float*)d_in[1];  // (8,32)
  const float* seg_b = (const float*)d_in[2];  // (8,)
  const float* lw = (const float*)d_in[3];     // (3,32)
  const float* lb = (const float*)d_in[4];     // (3,)

  float* out = (float*)d_out;
  float* logits_out = out;                // 48 floats
  float* masks_out = out + BS * NM * NK;  // 262144 floats, 192 B offset
  float* part = (float*)d_ws;             // 512 x 256 floats = 0.5 MB

  fused_kernel<<<NBLK, 512, 0, stream>>>(dec, seg_w, seg_b, masks_out, part);
  reduce_head_kernel<<<BS * NM, 1024, 0, stream>>>(part, lw, lb, logits_out);
}

// Round 8
// 102.458 us; speedup vs baseline: 1.1021x; 1.0137x over previous
//
#include <hip/hip_runtime.h>

// Problem constants (from reference)
#define BS 2
#define NF 16
#define CH 32
#define HW 16384      // 128*128
#define NM 8          // NUM_MASKS
#define NK 3          // NUM_CLASSES
#define MID 8         // NF/2

#define S 64          // spatial px per block
#define BPB (HW / S)  // partial rows per batch = 256
#define NBLK (BS * BPB)  // 512 blocks

// ---------------------------------------------------------------------------
// Fused kernel, round-8: R7 + STREAMING FMA ORDER.
//   R7's pool loop was m-outer/f-inner: the first m iteration consumed all
//   16 x[f] -> full vmcnt drain before any FMA. Now f-outer/m-inner with
//   the 8 mask float4 hoisted to registers: FMAs issue in load-retirement
//   (FIFO) order -- x[0] needs only vmcnt(14) -- so the FMA phase overlaps
//   the tail of the load stream. x[MID] issued first so the mid LDS-write
//   waits vmcnt(15) and 15 loads stay in flight under the mask phase.
//   VGPR ~ 64(x)+32(w)+8(acc)+addr ~ 118 < 128 cap of (512,4).
// ---------------------------------------------------------------------------
__global__ __launch_bounds__(512, 4) void fused_kernel(
    const float* __restrict__ dec, const float* __restrict__ seg_w,
    const float* __restrict__ seg_b, float* __restrict__ masks_out,
    float* __restrict__ part) {
  __shared__ float mid[CH][S];    // 8 KB
  __shared__ float msk[NM][S];    // 2 KB
  __shared__ float pbuf[NM * CH]; // 1 KB

  int t = threadIdx.x;
  int bid = blockIdx.x;           // 0..511
  int b = bid >> 8;
  int chunk = bid & 255;
  int cs = chunk * S;

  int s = t & 15;                 // spatial lane (16 x float4 = 64 px)
  int c = t >> 4;                 // channel 0..31

  // --- 0. issue loads: MID first (oldest in FIFO), then f=0..15 ---
  const float* base = dec + ((size_t)(b * NF) * CH + c) * HW + cs + s * 4;
  float4 x[NF];
  x[MID] = *(const float4*)(base + (size_t)MID * CH * HW);
#pragma unroll
  for (int f = 0; f < NF; ++f)
    if (f != MID) x[f] = *(const float4*)(base + (size_t)f * CH * HW);

  // --- 1. stage mid chunk to LDS (waits only the oldest load) ---
  *(float4*)&mid[c][s * 4] = x[MID];
  __syncthreads();

  // --- 2. masks: 512 values, 1/thread; 15 pool loads still in flight ---
  {
    int m = t >> 6, px = t & 63;
    float v = seg_b[m];
#pragma unroll
    for (int cc = 0; cc < CH; ++cc) v += mid[cc][px] * seg_w[m * CH + cc];
    msk[m][px] = v;
    masks_out[(size_t)b * NM * HW + (size_t)m * HW + cs + px] = v;
  }
  __syncthreads();

  // --- 3. pool FMAs: f-outer/m-inner streams in load-retirement order ---
  float4 w[NM];
#pragma unroll
  for (int m = 0; m < NM; ++m) w[m] = *(const float4*)&msk[m][s * 4];

  float acc[NM];
#pragma unroll
  for (int m = 0; m < NM; ++m) acc[m] = 0.f;
#pragma unroll
  for (int f = 0; f < NF; ++f)
#pragma unroll
    for (int m = 0; m < NM; ++m)
      acc[m] += x[f].x * w[m].x + x[f].y * w[m].y + x[f].z * w[m].z +
                x[f].w * w[m].w;

  // --- 4. reduce across 16 spatial lanes -> LDS -> coalesced 1KB write ---
#pragma unroll
  for (int off = 8; off >= 1; off >>= 1)
#pragma unroll
    for (int m = 0; m < NM; ++m) acc[m] += __shfl_down(acc[m], off, 16);

  if (s == 0)
#pragma unroll
    for (int m = 0; m < NM; ++m) pbuf[m * CH + c] = acc[m];
  __syncthreads();
  if (t < NM * CH) part[(size_t)bid * (NM * CH) + t] = pbuf[t];
}

// ---------------------------------------------------------------------------
// Reduce + head: one block per (b,m), 1024 threads (32-way split over the
// 256 partial rows -> 8 strided loads/thread), then the NK-logit head.
// ---------------------------------------------------------------------------
__global__ __launch_bounds__(1024) void reduce_head_kernel(
    const float* __restrict__ part, const float* __restrict__ lw,
    const float* __restrict__ lb, float* __restrict__ out) {
  __shared__ float red[32][CH];   // 4 KB
  __shared__ float pooled[CH];

  int t = threadIdx.x;
  int b = blockIdx.x >> 3;        // 0..1
  int m = blockIdx.x & 7;         // 0..7

  int c = t & 31, j = t >> 5;     // j: 32-way split over 256 partials
  float sum = 0.f;
  const float* p = part + (size_t)b * BPB * (NM * CH) + m * CH + c;
  for (int i = j; i < BPB; i += 32)   // 8 iterations, coalesced in c
    sum += p[(size_t)i * (NM * CH)];
  red[j][c] = sum;
  __syncthreads();

  if (t < CH) {
    float v = 0.f;
#pragma unroll
    for (int jj = 0; jj < 32; ++jj) v += red[jj][t];
    pooled[t] = v * (1.0f / NF);
  }
  __syncthreads();

  if (t < NK) {
    float dot = 0.f;
#pragma unroll
    for (int cc = 0; cc < CH; ++cc) dot += pooled[cc] * lw[t * CH + cc];
    out[b * (NM * NK) + m * NK + t] = dot + lb[t];
  }
}

extern "C" void kernel_launch(void* const* d_in, const int* in_sizes, int n_in,
                              void* d_out, int out_size, void* d_ws,
                              size_t ws_size, hipStream_t stream) {
  const float* dec = (const float*)d_in[0];    // (2,16,32,128,128)
  const float* seg_w = (const float*)d_in[1];  // (8,32)
  const float* seg_b = (const float*)d_in[2];  // (8,)
  const float* lw = (const float*)d_in[3];     // (3,32)
  const float* lb = (const float*)d_in[4];     // (3,)

  float* out = (float*)d_out;
  float* logits_out = out;                // 48 floats
  float* masks_out = out + BS * NM * NK;  // 262144 floats, 192 B offset
  float* part = (float*)d_ws;             // 512 x 256 floats = 0.5 MB

  fused_kernel<<<NBLK, 512, 0, stream>>>(dec, seg_w, seg_b, masks_out, part);
  reduce_head_kernel<<<BS * NM, 1024, 0, stream>>>(part, lw, lb, logits_out);
}